// Round 1
// baseline (1524.126 us; speedup 1.0000x reference)
//
#include <hip/hip_runtime.h>

// Problem constants (fixed by the reference file)
#define NND 50000   // nodes
#define NE  600000  // edges
#define TSEQ 50     // sequence length
#define NB  1000    // batch = NND/TSEQ

// ---------------------------------------------------------------- helpers
__device__ __forceinline__ float sigf(float x) {
    return 1.0f / (1.0f + __expf(-x));
}
__device__ __forceinline__ float tanhfast(float x) {
    x = fminf(fmaxf(x, -15.f), 15.f);
    float e = __expf(2.f * x);
    return (e - 1.f) / (e + 1.f);
}

// ---------------------------------------------------------------- degree
__global__ void k_deg(const int* __restrict__ ei, float* __restrict__ deg) {
    int e = blockIdx.x * 256 + threadIdx.x;
    if (e < NE) unsafeAtomicAdd(&deg[ei[NE + e]], 1.0f);
}

__global__ void k_dinv(float* __restrict__ deg) {
    int i = blockIdx.x * 256 + threadIdx.x;
    if (i < NND) deg[i] = 1.0f / sqrtf(deg[i] + 1.0f);
}

// ---------------------------------------------------------------- GEMM
// C[M x Nc] = A[M x 128] @ B[128 x Nc] (+bias). 64x64 tile, 256 thr, 4x4/thr.
__global__ __launch_bounds__(256) void k_gemm(
    const float* __restrict__ A, const float* __restrict__ B,
    const float* __restrict__ bias, float* __restrict__ C,
    int M, int Nc)
{
    __shared__ float As[64][65];   // [row][k], +1 pad
    __shared__ float Bs[64][64];   // [k][col]
    const int tid = threadIdx.x;
    const int tx = tid & 15, ty = tid >> 4;
    const int rowBase = blockIdx.x * 64;
    const int colBase = blockIdx.y * 64;
    float acc[4][4] = {};

    for (int kc = 0; kc < 128; kc += 64) {
        {   // stage A (coalesced float4 along k), store [row][k]
            int r  = tid >> 4;           // 0..15
            int k0 = (tid & 15) * 4;     // 0..60
            #pragma unroll
            for (int rr = 0; rr < 4; ++rr) {
                int lrow = rr * 16 + r;
                int row  = rowBase + lrow;
                float4 av = make_float4(0.f, 0.f, 0.f, 0.f);
                if (row < M) av = *(const float4*)&A[(size_t)row * 128 + kc + k0];
                As[lrow][k0 + 0] = av.x;
                As[lrow][k0 + 1] = av.y;
                As[lrow][k0 + 2] = av.z;
                As[lrow][k0 + 3] = av.w;
            }
        }
        {   // stage B
            int c0 = (tid & 15) * 4;
            #pragma unroll
            for (int it = 0; it < 4; ++it) {
                int kk = it * 16 + (tid >> 4);
                float4 bv = *(const float4*)&B[(size_t)(kc + kk) * Nc + colBase + c0];
                *(float4*)&Bs[kk][c0] = bv;
            }
        }
        __syncthreads();
        #pragma unroll
        for (int kk = 0; kk < 64; ++kk) {
            float4 bv = *(float4*)&Bs[kk][tx * 4];
            float a0 = As[ty * 4 + 0][kk];
            float a1 = As[ty * 4 + 1][kk];
            float a2 = As[ty * 4 + 2][kk];
            float a3 = As[ty * 4 + 3][kk];
            acc[0][0] += a0 * bv.x; acc[0][1] += a0 * bv.y; acc[0][2] += a0 * bv.z; acc[0][3] += a0 * bv.w;
            acc[1][0] += a1 * bv.x; acc[1][1] += a1 * bv.y; acc[1][2] += a1 * bv.z; acc[1][3] += a1 * bv.w;
            acc[2][0] += a2 * bv.x; acc[2][1] += a2 * bv.y; acc[2][2] += a2 * bv.z; acc[2][3] += a2 * bv.w;
            acc[3][0] += a3 * bv.x; acc[3][1] += a3 * bv.y; acc[3][2] += a3 * bv.z; acc[3][3] += a3 * bv.w;
        }
        __syncthreads();
    }

    int c0 = colBase + tx * 4;
    float4 bv = bias ? *(const float4*)&bias[c0] : make_float4(0.f, 0.f, 0.f, 0.f);
    #pragma unroll
    for (int i = 0; i < 4; ++i) {
        int row = rowBase + ty * 4 + i;
        if (row < M) {
            float4 o;
            o.x = acc[i][0] + bv.x;
            o.y = acc[i][1] + bv.y;
            o.z = acc[i][2] + bv.z;
            o.w = acc[i][3] + bv.w;
            *(float4*)&C[(size_t)row * Nc + c0] = o;
        }
    }
}

// ---------------------------------------------------------------- GCN pieces
__global__ void k_self(const float* __restrict__ h, const float* __restrict__ dinv,
                       float* __restrict__ agg) {
    int i = blockIdx.x * 256 + threadIdx.x;   // grid exactly NND*128
    float di = dinv[i >> 7];
    agg[i] = h[i] * di * di;
}

__global__ __launch_bounds__(256) void k_scatter(
    const int* __restrict__ ei, const float* __restrict__ h,
    const float* __restrict__ dinv, float* __restrict__ agg)
{
    int e = blockIdx.x * 2 + (threadIdx.x >> 7);
    int j = threadIdx.x & 127;
    int s = ei[e], d = ei[NE + e];
    float nm = dinv[s] * dinv[d];
    unsafeAtomicAdd(&agg[(size_t)d * 128 + j], h[(size_t)s * 128 + j] * nm);
}

__global__ void k_bias_relu(const float* __restrict__ agg, const float* __restrict__ b,
                            float* __restrict__ x) {
    int i = blockIdx.x * 256 + threadIdx.x;
    float v = agg[i] + b[i & 127];
    x[i] = v > 0.f ? v : 0.f;
}

// ---------------------------------------------------------------- LSTM prep
// Pack w (512x128 row-major, row r=g*128+j) into wp[k*512 + j*4 + g] so one
// float4 read at (k, j) yields (i,f,g,o) weights for hidden unit j.
__global__ void k_prep(const float* __restrict__ w_ih, const float* __restrict__ w_hh,
                       const float* __restrict__ b_ih, const float* __restrict__ b_hh,
                       float* __restrict__ wp_ih, float* __restrict__ wp_hh,
                       float* __restrict__ bp)
{
    int t = blockIdx.x * 256 + threadIdx.x;
    if (t < 65536) {
        int r = t >> 7, k = t & 127;
        int g = r >> 7, j = r & 127;
        wp_ih[k * 512 + (j << 2) + g] = w_ih[t];
    } else if (t < 131072) {
        int t2 = t - 65536;
        int r = t2 >> 7, k = t2 & 127;
        int g = r >> 7, j = r & 127;
        wp_hh[k * 512 + (j << 2) + g] = w_hh[t2];
    } else if (t < 131584) {
        int r = t - 131072;   // 0..511
        int g = r >> 7, j = r & 127;
        bp[(j << 2) + g] = b_ih[r] + b_hh[r];
    }
}

// ---------------------------------------------------------------- LSTM recurrence
// 4 batch elems / WG, 250 WGs. Thread (jt, half): half owns k-range, computes
// partials for all 4 b; combine via LDS; (jt,half) owns c/h for b = 2*half+{0,1}.
__global__ __launch_bounds__(256) void k_lstm(
    const float* __restrict__ G,    // (NB*TSEQ) x 512, gate-packed cols
    const float* __restrict__ wp,   // 128 x 512, gate-packed
    float* __restrict__ Hout)       // (NB*TSEQ) x 128
{
    const int tid  = threadIdx.x;
    const int jt   = tid & 127;
    const int half = tid >> 7;
    const int b0   = blockIdx.x * 4;
    __shared__ float h_s[4][128];
    __shared__ float part[2][4][4][128];   // [half][b][gate][jt]
    float c[2] = {0.f, 0.f};

    h_s[half * 2 + 0][jt] = 0.f;
    h_s[half * 2 + 1][jt] = 0.f;
    __syncthreads();

    for (int step = 0; step < TSEQ; ++step) {
        float acc[4][4] = {};   // [b][gate]
        const int kbase = half * 64;
        #pragma unroll
        for (int k2 = 0; k2 < 64; k2 += 4) {
            const int k = kbase + k2;
            float4 wv0 = *(const float4*)&wp[(size_t)(k + 0) * 512 + (jt << 2)];
            float4 wv1 = *(const float4*)&wp[(size_t)(k + 1) * 512 + (jt << 2)];
            float4 wv2 = *(const float4*)&wp[(size_t)(k + 2) * 512 + (jt << 2)];
            float4 wv3 = *(const float4*)&wp[(size_t)(k + 3) * 512 + (jt << 2)];
            #pragma unroll
            for (int b = 0; b < 4; ++b) {
                float4 hv = *(const float4*)&h_s[b][k];
                acc[b][0] += hv.x * wv0.x + hv.y * wv1.x + hv.z * wv2.x + hv.w * wv3.x;
                acc[b][1] += hv.x * wv0.y + hv.y * wv1.y + hv.z * wv2.y + hv.w * wv3.y;
                acc[b][2] += hv.x * wv0.z + hv.y * wv1.z + hv.z * wv2.z + hv.w * wv3.z;
                acc[b][3] += hv.x * wv0.w + hv.y * wv1.w + hv.z * wv2.w + hv.w * wv3.w;
            }
        }
        #pragma unroll
        for (int b = 0; b < 4; ++b)
            #pragma unroll
            for (int g = 0; g < 4; ++g)
                part[half][b][g][jt] = acc[b][g];
        __syncthreads();

        float hnew[2];
        #pragma unroll
        for (int bb = 0; bb < 2; ++bb) {
            int b = half * 2 + bb;
            float4 gv = *(const float4*)&G[(((size_t)(b0 + b)) * TSEQ + step) * 512 + (jt << 2)];
            float xi = part[0][b][0][jt] + part[1][b][0][jt] + gv.x;
            float xf = part[0][b][1][jt] + part[1][b][1][jt] + gv.y;
            float xg = part[0][b][2][jt] + part[1][b][2][jt] + gv.z;
            float xo = part[0][b][3][jt] + part[1][b][3][jt] + gv.w;
            float ii = sigf(xi), ff = sigf(xf), gg = tanhfast(xg), oo = sigf(xo);
            float cn = ff * c[bb] + ii * gg;
            c[bb] = cn;
            hnew[bb] = oo * tanhfast(cn);
        }
        // h_s reads for this step finished before the barrier above
        h_s[half * 2 + 0][jt] = hnew[0];
        h_s[half * 2 + 1][jt] = hnew[1];
        Hout[(((size_t)(b0 + half * 2 + 0)) * TSEQ + step) * 128 + jt] = hnew[0];
        Hout[(((size_t)(b0 + half * 2 + 1)) * TSEQ + step) * 128 + jt] = hnew[1];
        __syncthreads();
    }
}

// ---------------------------------------------------------------- FC head
__global__ __launch_bounds__(256) void k_fc(
    const float* __restrict__ seq, const float* __restrict__ fcw,
    const float* __restrict__ fcb, float* __restrict__ out)
{
    int b    = blockIdx.x * 4 + (threadIdx.x >> 6);
    int lane = threadIdx.x & 63;
    const float* row = &seq[(((size_t)b) * TSEQ + (TSEQ - 1)) * 128];
    float v = row[lane] * fcw[lane] + row[lane + 64] * fcw[lane + 64];
    #pragma unroll
    for (int off = 32; off > 0; off >>= 1)
        v += __shfl_down(v, off);
    if (lane == 0) out[b] = v + fcb[0];
}

// ---------------------------------------------------------------- launch
extern "C" void kernel_launch(void* const* d_in, const int* in_sizes, int n_in,
                              void* d_out, int out_size, void* d_ws, size_t ws_size,
                              hipStream_t stream)
{
    const float* x    = (const float*)d_in[0];
    const int*   ei   = (const int*)d_in[1];
    const float* W1   = (const float*)d_in[3];
    const float* b1   = (const float*)d_in[4];
    const float* W2   = (const float*)d_in[5];
    const float* b2   = (const float*)d_in[6];
    const float* fcw  = (const float*)d_in[7];
    const float* fcb  = (const float*)d_in[8];
    const float* wih0 = (const float*)d_in[9];
    const float* whh0 = (const float*)d_in[10];
    const float* bih0 = (const float*)d_in[11];
    const float* bhh0 = (const float*)d_in[12];
    const float* wih1 = (const float*)d_in[13];
    const float* whh1 = (const float*)d_in[14];
    const float* bih1 = (const float*)d_in[15];
    const float* bhh1 = (const float*)d_in[16];
    float* out = (float*)d_out;

    char* ws = (char*)d_ws;
    float* bufH  = (float*)(ws + 0);           // 25.6 MB  (h pre-agg / seq0)
    float* bufX  = (float*)(ws + 25600000);    // 25.6 MB  (agg / X / seq1)
    float* bufG  = (float*)(ws + 51200000);    // 102.4 MB (gates)
    float* dinv  = (float*)(ws + 153600000);   // 0.2 MB   (deg -> dinv in place)
    float* wpih0 = (float*)(ws + 153800192);
    float* wphh0 = (float*)(ws + 154062336);
    float* wpih1 = (float*)(ws + 154324480);
    float* wphh1 = (float*)(ws + 154586624);
    float* bp0   = (float*)(ws + 154848768);
    float* bp1   = (float*)(ws + 154850816);

    // degree -> dinv
    hipMemsetAsync(dinv, 0, NND * sizeof(float), stream);
    k_deg<<<(NE + 255) / 256, 256, 0, stream>>>(ei, dinv);
    k_dinv<<<(NND + 255) / 256, 256, 0, stream>>>(dinv);

    // pack LSTM weights
    k_prep<<<514, 256, 0, stream>>>(wih0, whh0, bih0, bhh0, wpih0, wphh0, bp0);
    k_prep<<<514, 256, 0, stream>>>(wih1, whh1, bih1, bhh1, wpih1, wphh1, bp1);

    dim3 gH((NND + 63) / 64, 2);   // 128-col GEMMs
    dim3 gG((NND + 63) / 64, 8);   // 512-col GEMMs

    // GCN layer 1
    k_gemm<<<gH, 256, 0, stream>>>(x, W1, nullptr, bufH, NND, 128);
    k_self<<<NND * 128 / 256, 256, 0, stream>>>(bufH, dinv, bufX);
    k_scatter<<<NE / 2, 256, 0, stream>>>(ei, bufH, dinv, bufX);
    k_bias_relu<<<NND * 128 / 256, 256, 0, stream>>>(bufX, b1, bufX);

    // GCN layer 2
    k_gemm<<<gH, 256, 0, stream>>>(bufX, W2, nullptr, bufH, NND, 128);
    k_self<<<NND * 128 / 256, 256, 0, stream>>>(bufH, dinv, bufX);
    k_scatter<<<NE / 2, 256, 0, stream>>>(ei, bufH, dinv, bufX);
    k_bias_relu<<<NND * 128 / 256, 256, 0, stream>>>(bufX, b2, bufX);

    // LSTM layer 0: gates for all timesteps, then recurrence (seq out -> bufH)
    k_gemm<<<gG, 256, 0, stream>>>(bufX, wpih0, bp0, bufG, NND, 512);
    k_lstm<<<NB / 4, 256, 0, stream>>>(bufG, wphh0, bufH);

    // LSTM layer 1 (seq out -> bufX)
    k_gemm<<<gG, 256, 0, stream>>>(bufH, wpih1, bp1, bufG, NND, 512);
    k_lstm<<<NB / 4, 256, 0, stream>>>(bufG, wphh1, bufX);

    // FC head
    k_fc<<<NB / 4, 256, 0, stream>>>(bufX, fcw, fcb, out);
}

// Round 2
// 1469.097 us; speedup vs baseline: 1.0375x; 1.0375x over previous
//
#include <hip/hip_runtime.h>

// Problem constants (fixed by the reference file)
#define NND 50000   // nodes
#define NE  600000  // edges
#define TSEQ 50     // sequence length
#define NB  1000    // batch = NND/TSEQ

// ---------------------------------------------------------------- helpers
__device__ __forceinline__ float sigf(float x) {
    return 1.0f / (1.0f + __expf(-x));
}
__device__ __forceinline__ float tanhfast(float x) {
    x = fminf(fmaxf(x, -15.f), 15.f);
    float e = __expf(2.f * x);
    return (e - 1.f) / (e + 1.f);
}

// ---------------------------------------------------------------- degree
__global__ void k_deg(const int* __restrict__ ei, float* __restrict__ deg) {
    int e = blockIdx.x * 256 + threadIdx.x;
    if (e < NE) unsafeAtomicAdd(&deg[ei[NE + e]], 1.0f);
}

__global__ void k_dinv(float* __restrict__ deg) {
    int i = blockIdx.x * 256 + threadIdx.x;
    if (i < NND) deg[i] = 1.0f / sqrtf(deg[i] + 1.0f);
}

// ---------------------------------------------------------------- GEMM
// C[M x Nc] = A[M x 128] @ B[128 x Nc] (+bias). 64x64 tile, 256 thr, 4x4/thr.
__global__ __launch_bounds__(256) void k_gemm(
    const float* __restrict__ A, const float* __restrict__ B,
    const float* __restrict__ bias, float* __restrict__ C,
    int M, int Nc)
{
    __shared__ float As[64][65];   // [row][k], +1 pad
    __shared__ float Bs[64][64];   // [k][col]
    const int tid = threadIdx.x;
    const int tx = tid & 15, ty = tid >> 4;
    const int rowBase = blockIdx.x * 64;
    const int colBase = blockIdx.y * 64;
    float acc[4][4] = {};

    for (int kc = 0; kc < 128; kc += 64) {
        {   // stage A (coalesced float4 along k), store [row][k]
            int r  = tid >> 4;           // 0..15
            int k0 = (tid & 15) * 4;     // 0..60
            #pragma unroll
            for (int rr = 0; rr < 4; ++rr) {
                int lrow = rr * 16 + r;
                int row  = rowBase + lrow;
                float4 av = make_float4(0.f, 0.f, 0.f, 0.f);
                if (row < M) av = *(const float4*)&A[(size_t)row * 128 + kc + k0];
                As[lrow][k0 + 0] = av.x;
                As[lrow][k0 + 1] = av.y;
                As[lrow][k0 + 2] = av.z;
                As[lrow][k0 + 3] = av.w;
            }
        }
        {   // stage B
            int c0 = (tid & 15) * 4;
            #pragma unroll
            for (int it = 0; it < 4; ++it) {
                int kk = it * 16 + (tid >> 4);
                float4 bv = *(const float4*)&B[(size_t)(kc + kk) * Nc + colBase + c0];
                *(float4*)&Bs[kk][c0] = bv;
            }
        }
        __syncthreads();
        #pragma unroll
        for (int kk = 0; kk < 64; ++kk) {
            float4 bv = *(float4*)&Bs[kk][tx * 4];
            float a0 = As[ty * 4 + 0][kk];
            float a1 = As[ty * 4 + 1][kk];
            float a2 = As[ty * 4 + 2][kk];
            float a3 = As[ty * 4 + 3][kk];
            acc[0][0] += a0 * bv.x; acc[0][1] += a0 * bv.y; acc[0][2] += a0 * bv.z; acc[0][3] += a0 * bv.w;
            acc[1][0] += a1 * bv.x; acc[1][1] += a1 * bv.y; acc[1][2] += a1 * bv.z; acc[1][3] += a1 * bv.w;
            acc[2][0] += a2 * bv.x; acc[2][1] += a2 * bv.y; acc[2][2] += a2 * bv.z; acc[2][3] += a2 * bv.w;
            acc[3][0] += a3 * bv.x; acc[3][1] += a3 * bv.y; acc[3][2] += a3 * bv.z; acc[3][3] += a3 * bv.w;
        }
        __syncthreads();
    }

    int c0 = colBase + tx * 4;
    float4 bv = bias ? *(const float4*)&bias[c0] : make_float4(0.f, 0.f, 0.f, 0.f);
    #pragma unroll
    for (int i = 0; i < 4; ++i) {
        int row = rowBase + ty * 4 + i;
        if (row < M) {
            float4 o;
            o.x = acc[i][0] + bv.x;
            o.y = acc[i][1] + bv.y;
            o.z = acc[i][2] + bv.z;
            o.w = acc[i][3] + bv.w;
            *(float4*)&C[(size_t)row * Nc + c0] = o;
        }
    }
}

// ---------------------------------------------------------------- GCN pieces
__global__ void k_self(const float* __restrict__ h, const float* __restrict__ dinv,
                       float* __restrict__ agg) {
    int i = blockIdx.x * 256 + threadIdx.x;   // grid exactly NND*128
    float di = dinv[i >> 7];
    agg[i] = h[i] * di * di;
}

__global__ __launch_bounds__(256) void k_scatter(
    const int* __restrict__ ei, const float* __restrict__ h,
    const float* __restrict__ dinv, float* __restrict__ agg)
{
    int e = blockIdx.x * 2 + (threadIdx.x >> 7);
    int j = threadIdx.x & 127;
    int s = ei[e], d = ei[NE + e];
    float nm = dinv[s] * dinv[d];
    unsafeAtomicAdd(&agg[(size_t)d * 128 + j], h[(size_t)s * 128 + j] * nm);
}

__global__ void k_bias_relu(const float* __restrict__ agg, const float* __restrict__ b,
                            float* __restrict__ x) {
    int i = blockIdx.x * 256 + threadIdx.x;
    float v = agg[i] + b[i & 127];
    x[i] = v > 0.f ? v : 0.f;
}

// ---------------------------------------------------------------- LSTM prep
// Pack w (512x128 row-major, row r=g*128+j) into wp[k*512 + j*4 + g] so one
// float4 read at (k, j) yields (i,f,g,o) weights for hidden unit j.
__global__ void k_prep(const float* __restrict__ w_ih, const float* __restrict__ w_hh,
                       const float* __restrict__ b_ih, const float* __restrict__ b_hh,
                       float* __restrict__ wp_ih, float* __restrict__ wp_hh,
                       float* __restrict__ bp)
{
    int t = blockIdx.x * 256 + threadIdx.x;
    if (t < 65536) {
        int r = t >> 7, k = t & 127;
        int g = r >> 7, j = r & 127;
        wp_ih[k * 512 + (j << 2) + g] = w_ih[t];
    } else if (t < 131072) {
        int t2 = t - 65536;
        int r = t2 >> 7, k = t2 & 127;
        int g = r >> 7, j = r & 127;
        wp_hh[k * 512 + (j << 2) + g] = w_hh[t2];
    } else if (t < 131584) {
        int r = t - 131072;   // 0..511
        int g = r >> 7, j = r & 127;
        bp[(j << 2) + g] = b_ih[r] + b_hh[r];
    }
}

// ---------------------------------------------------------------- LSTM recurrence
// v2: weights in VGPRs. 512 threads/WG, 4 batch elems/WG, 250 WGs.
// Phase 1: thread t owns packed gate-col p=t, holds all 128 w_hh weights for
//   that column in registers (loop-invariant across the 50 steps), streams h
//   from LDS (wave-uniform broadcast reads) -> acc[b] for 4 batches.
// Phase 2: thread t remaps to (j=t&127, b=t>>7), combines i,f,g,o via LDS,
//   owns the (b,j) c-state in a register.
__global__ __launch_bounds__(512, 2) void k_lstm(
    const float* __restrict__ G,    // (NB*TSEQ) x 512, gate-packed cols
    const float* __restrict__ wp,   // 128 x 512, gate-packed
    float* __restrict__ Hout)       // (NB*TSEQ) x 128
{
    const int t  = threadIdx.x;       // 0..511 = packed gate column
    const int j  = t & 127;           // phase-2 hidden unit
    const int b  = t >> 7;            // phase-2 batch slot
    const int b0 = blockIdx.x * 4;

    __shared__ float h_s[4][128];     // [batch][hidden]
    __shared__ float part[4][512];    // [batch][packed gate col]

    // load the thread's weight column into registers (stays for all 50 steps)
    float4 wreg[32];
    #pragma unroll
    for (int k2 = 0; k2 < 32; ++k2) {
        float4 w;
        w.x = wp[(size_t)(k2 * 4 + 0) * 512 + t];
        w.y = wp[(size_t)(k2 * 4 + 1) * 512 + t];
        w.z = wp[(size_t)(k2 * 4 + 2) * 512 + t];
        w.w = wp[(size_t)(k2 * 4 + 3) * 512 + t];
        wreg[k2] = w;
    }

    h_s[b][j] = 0.f;
    float c = 0.f;
    __syncthreads();

    const float* gbase = &G[(((size_t)(b0 + b)) * TSEQ) * 512 + (j << 2)];

    for (int step = 0; step < TSEQ; ++step) {
        // prefetch this thread's gate-input quad (phase-2 mapping)
        const float4 gv = *(const float4*)&gbase[(size_t)step * 512];

        // phase 1: acc[b'] = sum_k h[b'][k] * w[k][t]
        float acc0 = 0.f, acc1 = 0.f, acc2 = 0.f, acc3 = 0.f;
        #pragma unroll
        for (int k2 = 0; k2 < 32; ++k2) {
            const float4 w = wreg[k2];
            float4 hv;
            hv = *(const float4*)&h_s[0][k2 * 4];
            acc0 += hv.x * w.x + hv.y * w.y + hv.z * w.z + hv.w * w.w;
            hv = *(const float4*)&h_s[1][k2 * 4];
            acc1 += hv.x * w.x + hv.y * w.y + hv.z * w.z + hv.w * w.w;
            hv = *(const float4*)&h_s[2][k2 * 4];
            acc2 += hv.x * w.x + hv.y * w.y + hv.z * w.z + hv.w * w.w;
            hv = *(const float4*)&h_s[3][k2 * 4];
            acc3 += hv.x * w.x + hv.y * w.y + hv.z * w.z + hv.w * w.w;
        }
        part[0][t] = acc0;
        part[1][t] = acc1;
        part[2][t] = acc2;
        part[3][t] = acc3;
        __syncthreads();

        // phase 2: thread (j,b) applies the LSTM cell
        const float4 pa = *(const float4*)&part[b][j << 2];
        float xi = pa.x + gv.x;
        float xf = pa.y + gv.y;
        float xg = pa.z + gv.z;
        float xo = pa.w + gv.w;
        float ii = sigf(xi), ff = sigf(xf), gg = tanhfast(xg), oo = sigf(xo);
        float cn = ff * c + ii * gg;
        c = cn;
        float hn = oo * tanhfast(cn);
        h_s[b][j] = hn;
        Hout[(((size_t)(b0 + b)) * TSEQ + step) * 128 + j] = hn;
        __syncthreads();
    }
}

// ---------------------------------------------------------------- FC head
__global__ __launch_bounds__(256) void k_fc(
    const float* __restrict__ seq, const float* __restrict__ fcw,
    const float* __restrict__ fcb, float* __restrict__ out)
{
    int b    = blockIdx.x * 4 + (threadIdx.x >> 6);
    int lane = threadIdx.x & 63;
    const float* row = &seq[(((size_t)b) * TSEQ + (TSEQ - 1)) * 128];
    float v = row[lane] * fcw[lane] + row[lane + 64] * fcw[lane + 64];
    #pragma unroll
    for (int off = 32; off > 0; off >>= 1)
        v += __shfl_down(v, off);
    if (lane == 0) out[b] = v + fcb[0];
}

// ---------------------------------------------------------------- launch
extern "C" void kernel_launch(void* const* d_in, const int* in_sizes, int n_in,
                              void* d_out, int out_size, void* d_ws, size_t ws_size,
                              hipStream_t stream)
{
    const float* x    = (const float*)d_in[0];
    const int*   ei   = (const int*)d_in[1];
    const float* W1   = (const float*)d_in[3];
    const float* b1   = (const float*)d_in[4];
    const float* W2   = (const float*)d_in[5];
    const float* b2   = (const float*)d_in[6];
    const float* fcw  = (const float*)d_in[7];
    const float* fcb  = (const float*)d_in[8];
    const float* wih0 = (const float*)d_in[9];
    const float* whh0 = (const float*)d_in[10];
    const float* bih0 = (const float*)d_in[11];
    const float* bhh0 = (const float*)d_in[12];
    const float* wih1 = (const float*)d_in[13];
    const float* whh1 = (const float*)d_in[14];
    const float* bih1 = (const float*)d_in[15];
    const float* bhh1 = (const float*)d_in[16];
    float* out = (float*)d_out;

    char* ws = (char*)d_ws;
    float* bufH  = (float*)(ws + 0);           // 25.6 MB  (h pre-agg / seq0)
    float* bufX  = (float*)(ws + 25600000);    // 25.6 MB  (agg / X / seq1)
    float* bufG  = (float*)(ws + 51200000);    // 102.4 MB (gates)
    float* dinv  = (float*)(ws + 153600000);   // 0.2 MB   (deg -> dinv in place)
    float* wpih0 = (float*)(ws + 153800192);
    float* wphh0 = (float*)(ws + 154062336);
    float* wpih1 = (float*)(ws + 154324480);
    float* wphh1 = (float*)(ws + 154586624);
    float* bp0   = (float*)(ws + 154848768);
    float* bp1   = (float*)(ws + 154850816);

    // degree -> dinv
    hipMemsetAsync(dinv, 0, NND * sizeof(float), stream);
    k_deg<<<(NE + 255) / 256, 256, 0, stream>>>(ei, dinv);
    k_dinv<<<(NND + 255) / 256, 256, 0, stream>>>(dinv);

    // pack LSTM weights
    k_prep<<<514, 256, 0, stream>>>(wih0, whh0, bih0, bhh0, wpih0, wphh0, bp0);
    k_prep<<<514, 256, 0, stream>>>(wih1, whh1, bih1, bhh1, wpih1, wphh1, bp1);

    dim3 gH((NND + 63) / 64, 2);   // 128-col GEMMs
    dim3 gG((NND + 63) / 64, 8);   // 512-col GEMMs

    // GCN layer 1
    k_gemm<<<gH, 256, 0, stream>>>(x, W1, nullptr, bufH, NND, 128);
    k_self<<<NND * 128 / 256, 256, 0, stream>>>(bufH, dinv, bufX);
    k_scatter<<<NE / 2, 256, 0, stream>>>(ei, bufH, dinv, bufX);
    k_bias_relu<<<NND * 128 / 256, 256, 0, stream>>>(bufX, b1, bufX);

    // GCN layer 2
    k_gemm<<<gH, 256, 0, stream>>>(bufX, W2, nullptr, bufH, NND, 128);
    k_self<<<NND * 128 / 256, 256, 0, stream>>>(bufH, dinv, bufX);
    k_scatter<<<NE / 2, 256, 0, stream>>>(ei, bufH, dinv, bufX);
    k_bias_relu<<<NND * 128 / 256, 256, 0, stream>>>(bufX, b2, bufX);

    // LSTM layer 0: gates for all timesteps, then recurrence (seq out -> bufH)
    k_gemm<<<gG, 256, 0, stream>>>(bufX, wpih0, bp0, bufG, NND, 512);
    k_lstm<<<NB / 4, 512, 0, stream>>>(bufG, wphh0, bufH);

    // LSTM layer 1 (seq out -> bufX)
    k_gemm<<<gG, 256, 0, stream>>>(bufH, wpih1, bp1, bufG, NND, 512);
    k_lstm<<<NB / 4, 512, 0, stream>>>(bufG, wphh1, bufX);

    // FC head
    k_fc<<<NB / 4, 256, 0, stream>>>(bufX, fcw, fcb, out);
}